// Round 8
// baseline (547.226 us; speedup 1.0000x reference)
//
#include <hip/hip_runtime.h>

#define H 128
#define EPS 1e-5f
#define NPB 256      // nodes per bucket (pow2); bucket = node >> 8

typedef __attribute__((ext_vector_type(8))) short bf16x8;
typedef __attribute__((ext_vector_type(4))) float f32x4;

__device__ inline unsigned short f2bf(float f){
  unsigned int u=__float_as_uint(f);
  return (unsigned short)((u + 0x7FFFu + ((u>>16)&1u))>>16);
}
__device__ inline unsigned int pack_bf16(float a, float b){
  unsigned int ua=__float_as_uint(a), ub=__float_as_uint(b);
  ua = (ua + 0x7FFFu + ((ua>>16)&1u)) >> 16;
  ub = (ub + 0x7FFFu + ((ub>>16)&1u)) & 0xFFFF0000u;
  return ua | ub;
}
__device__ inline float bflo(unsigned int u){ return __uint_as_float(u<<16); }
__device__ inline float bfhi(unsigned int u){ return __uint_as_float(u&0xFFFF0000u); }

// ============ CSR build v2: direct 2-pass (round-8) ============
// Old 4-pass bucket sort (bcount/bfill/p2a/p2b) did 4 full E-passes + a 13MB stg
// intermediate; bfill's LDS histograms + scattered stg writes were the k_g1bf critical
// path (3 gemm variants -> same 85us). New: deg[] (400KB, L2-resident) via global
// atomics; per-bucket LDS scan of deg -> rowptr/cur/dnorm; placement scatters pairs
// directly via cur atomics. One edge pass for placement, zero LDS histograms, no stg.

__device__ __forceinline__ void degcount_body(const int* __restrict__ col, int E,
                                              int* __restrict__ deg, int bid){
  int e0=bid*4096, e1=min(e0+4096,E);
  for(int e=e0+threadIdx.x;e<e1;e+=256) atomicAdd(&deg[col[e]],1);
}

// ---- one-time W transpose+convert: Wt[m][c*136+k] = bf16(W_m[k][c]) ----
__device__ __forceinline__ void wconv_body(const float* __restrict__ W0,
    const float* __restrict__ W1, unsigned short* __restrict__ Wt, int bid){
  int m=bid>>6;
  int lin=((bid&63)<<8)+threadIdx.x;            // 0..16383
  const float* src = (m==0) ? W0 : (W1 + (size_t)(m-1)*16384);
  int k=lin>>7, c=lin&127;
  Wt[(size_t)m*17408 + c*136 + k] = f2bf(src[lin]);
}

// ---- packed: [wconv (GW blocks) | degcount] ----
__global__ __launch_bounds__(256) void k_wb(const float* __restrict__ W0,
    const float* __restrict__ W1, unsigned short* __restrict__ Wt, int GW,
    const int* __restrict__ col, int E, int* __restrict__ deg){
  int bid=blockIdx.x;
  if(bid<GW) wconv_body(W0,W1,Wt,bid);
  else       degcount_body(col,E,deg,bid-GW);
}

// ---- per-bucket degree totals (LDS reduce) ----
__global__ __launch_bounds__(256) void k_btot(const int* __restrict__ deg, int N,
                                              int* __restrict__ btot){
  __shared__ int s[256];
  int t=threadIdx.x;
  int node=(blockIdx.x<<8)+t;
  s[t]=(node<N)?deg[node]:0;
  __syncthreads();
  for(int off=128;off>0;off>>=1){ if(t<off) s[t]+=s[t+off]; __syncthreads(); }
  if(t==0) btot[blockIdx.x]=s[0];
}

// ---- exclusive scan of bucket totals (single block, B<=512) ----
__global__ void k_bscan(const int* __restrict__ btot, int B, int E,
                        int* __restrict__ bbase){
  __shared__ int s[512];
  int t=threadIdx.x;
  int v=(t<B)?btot[t]:0;
  s[t]=v; __syncthreads();
  for(int off=1;off<512;off<<=1){ int u=(t>=off)?s[t-off]:0; __syncthreads(); s[t]+=u; __syncthreads(); }
  if(t<B) bbase[t]=s[t]-v;
  if(t==0) bbase[B]=E;
}

// ---- per-bucket: deg -> rowptr, cur, dnorm (LDS scan over 256 nodes) ----
__global__ __launch_bounds__(256) void k_p2a(const int* __restrict__ deg,
    const int* __restrict__ bbase, int N, int E,
    float* __restrict__ dnorm, int* __restrict__ rowptr, int* __restrict__ cur){
  __shared__ int pre[256];
  int b=blockIdx.x, t=threadIdx.x;
  int node=(b<<8)+t;
  int v=(node<N)?deg[node]:0;
  pre[t]=v; __syncthreads();
  for(int off=1;off<256;off<<=1){ int u=(t>=off)?pre[t-off]:0; __syncthreads(); pre[t]+=u; __syncthreads(); }
  if(node<N){
    int rp=bbase[b]+pre[t]-v;
    dnorm[node]= v>0 ? rsqrtf((float)v) : 0.f;   // nan_to_num: deg==0 -> coefficient 0
    rowptr[node]=rp;
    cur[node]=rp;
    if(node==N-1) rowptr[N]=E;
  }
}

// ---- placement: pairs[atomic cur[dest]++] = (row, ew*dnorm[row]) ----
// cur is 400KB (L2-resident); pairs 12.8MB mostly L2-resident. Single edge pass.
__device__ __forceinline__ void place_body(const int* __restrict__ row,
    const int* __restrict__ col, const float* __restrict__ ew, int E,
    int* __restrict__ cur, const float* __restrict__ dnorm,
    float2* __restrict__ pairs, int bid){
  int e0=bid*4096, e1=min(e0+4096,E);
  for(int e=e0+threadIdx.x;e<e1;e+=256){
    int d=col[e], r=row[e];
    int pos=atomicAdd(&cur[d],1);
    pairs[pos]=make_float2(__int_as_float(r), ew[e]*dnorm[r]);
  }
}

// ---------------- SpMM bf16: wave/dest, 2 cols/lane, 16 gathers in flight ----------------
// Proven v8 body (60.6us; best of 4 structural attempts — do not touch). Edge
// bookkeeping is fully scalar: pairs loads are wave-uniform s_load; gather = SGPR base
// + fixed lane offset; weight is an SGPR fma operand. v10 lesson: per-lane edge
// addressing doubles VALU time. v11 lesson: masked-full-batch tail adds ~50% edge work.
// BN0 applies stage-0 BN+ReLU inline to each gathered value (gather source = raw z0).
template<bool BN0>
__global__ __launch_bounds__(256) void k_spmm_bf(const float2* __restrict__ pairs,
    const int* __restrict__ rowptr, const float* __restrict__ dnorm,
    const unsigned short* __restrict__ hb, unsigned short* __restrict__ zb, int N,
    const float* __restrict__ bnst, const float* __restrict__ gamma,
    const float* __restrict__ beta, float invN){
  int wid=(blockIdx.x*256+threadIdx.x)>>6;
  int lane=threadIdx.x&63;
  if(wid>=N) return;
  float sc0=0.f,sh0=0.f,sc1=0.f,sh1=0.f;
  if(BN0){
    int c0=lane<<1;
    float m0=bnst[c0]*invN,      m1=bnst[c0+1]*invN;
    float v0=bnst[128+c0]*invN-m0*m0, v1=bnst[129+c0]*invN-m1*m1;
    sc0=rsqrtf(v0+EPS)*gamma[c0];   sh0=beta[c0]-m0*sc0;
    sc1=rsqrtf(v1+EPS)*gamma[c0+1]; sh1=beta[c0+1]-m1*sc1;
  }
  int beg=__builtin_amdgcn_readfirstlane(rowptr[wid]);
  int end=__builtin_amdgcn_readfirstlane(rowptr[wid+1]);
  float ax=0.f, ay=0.f;
  int p=beg;
  for(; p+16<=end; p+=16){
    float2 pr[16]; unsigned int u[16];
    #pragma unroll
    for(int j=0;j<16;j++) pr[j]=pairs[p+j];
    #pragma unroll
    for(int j=0;j<16;j++)
      u[j]=*(const unsigned int*)(hb + (((size_t)__float_as_int(pr[j].x))<<7) + (lane<<1));
    #pragma unroll
    for(int j=0;j<16;j++){
      float f0=bflo(u[j]), f1=bfhi(u[j]);
      if(BN0){ f0=fmaxf(fmaf(f0,sc0,sh0),0.f); f1=fmaxf(fmaf(f1,sc1,sh1),0.f); }
      ax=fmaf(pr[j].y,f0,ax); ay=fmaf(pr[j].y,f1,ay);
    }
  }
  for(; p+4<=end; p+=4){
    float2 pr[4]; unsigned int u[4];
    #pragma unroll
    for(int j=0;j<4;j++) pr[j]=pairs[p+j];
    #pragma unroll
    for(int j=0;j<4;j++)
      u[j]=*(const unsigned int*)(hb + (((size_t)__float_as_int(pr[j].x))<<7) + (lane<<1));
    #pragma unroll
    for(int j=0;j<4;j++){
      float f0=bflo(u[j]), f1=bfhi(u[j]);
      if(BN0){ f0=fmaxf(fmaf(f0,sc0,sh0),0.f); f1=fmaxf(fmaf(f1,sc1,sh1),0.f); }
      ax=fmaf(pr[j].y,f0,ax); ay=fmaf(pr[j].y,f1,ay);
    }
  }
  for(; p<end; ++p){
    float2 pr=pairs[p];
    unsigned int u=*(const unsigned int*)(hb + (((size_t)__float_as_int(pr.x))<<7) + (lane<<1));
    float f0=bflo(u), f1=bfhi(u);
    if(BN0){ f0=fmaxf(fmaf(f0,sc0,sh0),0.f); f1=fmaxf(fmaf(f1,sc1,sh1),0.f); }
    ax=fmaf(pr.y,f0,ax); ay=fmaf(pr.y,f1,ay);
  }
  float dn=dnorm[wid];
  *(unsigned int*)(zb + ((size_t)wid<<7) + (lane<<1)) = pack_bf16(ax*dn, ay*dn);
}

// ---------------- MFMA GEMM body (128 rows/block @ 128x128) + fused BN sum/sumsq ----------------
// Round-7 body: no LDS W-staging (Wt 34KB is L1/L2-hot across all blocks); LDS only
// for stats partials; A prefetched up front. In-place safe. Layouts: A m=lane&15,
// k=quad*8+j; C/D col=lane&15, row=quad*4+reg [m89/m120-verified].
template<bool F32A>
__device__ __forceinline__ void gemm_bn_body(const void* __restrict__ Ap,
    const unsigned short* __restrict__ Wt, const float* __restrict__ bias,
    unsigned short* __restrict__ Zb, float* __restrict__ stats, int N,
    int bid, char* smem){
  int t=threadIdx.x;
  int w=t>>6, lane=t&63, n=lane&15, quad=lane>>4;
  int r0w = bid*128 + w*32;

  bf16x8 a[4][2];
  if(F32A){
    const float* Af=(const float*)Ap;
    float4 uf[4][2][2];
    #pragma unroll
    for(int ks=0;ks<4;ks++){
      int k0=ks*32+quad*8;
      #pragma unroll
      for(int rt=0;rt<2;rt++){
        int r=r0w+rt*16+n;
        if(r<N){
          uf[ks][rt][0]=*(const float4*)&Af[(size_t)r*128+k0];
          uf[ks][rt][1]=*(const float4*)&Af[(size_t)r*128+k0+4];
        }else{
          float4 z4={0.f,0.f,0.f,0.f}; uf[ks][rt][0]=z4; uf[ks][rt][1]=z4;
        }
      }
    }
    #pragma unroll
    for(int ks=0;ks<4;ks++)
      #pragma unroll
      for(int rt=0;rt<2;rt++){
        float4 u0=uf[ks][rt][0], u1=uf[ks][rt][1];
        bf16x8 af;
        af[0]=(short)f2bf(u0.x); af[1]=(short)f2bf(u0.y);
        af[2]=(short)f2bf(u0.z); af[3]=(short)f2bf(u0.w);
        af[4]=(short)f2bf(u1.x); af[5]=(short)f2bf(u1.y);
        af[6]=(short)f2bf(u1.z); af[7]=(short)f2bf(u1.w);
        a[ks][rt]=af;
      }
  }else{
    const unsigned short* Ab=(const unsigned short*)Ap;
    #pragma unroll
    for(int ks=0;ks<4;ks++){
      int k0=ks*32+quad*8;
      #pragma unroll
      for(int rt=0;rt<2;rt++){
        int r=r0w+rt*16+n;
        bf16x8 af={0,0,0,0,0,0,0,0};
        if(r<N) af = *(const bf16x8*)(Ab + (size_t)r*128 + k0);
        a[ks][rt]=af;
      }
    }
  }

  f32x4 acc[8][2];
  #pragma unroll
  for(int nt=0;nt<8;nt++)
    #pragma unroll
    for(int rt=0;rt<2;rt++){ f32x4 z4={0.f,0.f,0.f,0.f}; acc[nt][rt]=z4; }

  #pragma unroll
  for(int ks=0; ks<4; ks++){
    int k0 = ks*32 + quad*8;
    #pragma unroll
    for(int nt=0;nt<8;nt++){
      bf16x8 b = *(const bf16x8*)&Wt[(size_t)(nt*16+n)*136 + k0];   // L1/L2-hot
      #pragma unroll
      for(int rt=0;rt<2;rt++)
        acc[nt][rt]=__builtin_amdgcn_mfma_f32_16x16x32_bf16(a[ks][rt], b, acc[nt][rt], 0,0,0);
    }
  }

  float* sS=(float*)smem;                 // [16][132]
  float* sQ=sS + 16*132;                  // [16][132]
  #pragma unroll
  for(int nt=0;nt<8;nt++){
    int c=nt*16+n;
    float bc=bias[c];
    float s=0.f,q=0.f;
    #pragma unroll
    for(int rt=0;rt<2;rt++){
      #pragma unroll
      for(int i=0;i<4;i++){
        int r=r0w + rt*16 + quad*4 + i;
        if(r<N){
          float z=acc[nt][rt][i]+bc;
          Zb[(size_t)r*128+c]=f2bf(z);
          s+=z; q+=z*z;
        }
      }
    }
    sS[(w*4+quad)*132+c]=s;
    sQ[(w*4+quad)*132+c]=q;
  }
  __syncthreads();
  if(t<128){
    float s=0.f,q=0.f;
    #pragma unroll
    for(int g=0;g<16;g++){ s+=sS[g*132+t]; q+=sQ[g*132+t]; }
    atomicAdd(&stats[t],s); atomicAdd(&stats[128+t],q);
  }
}

// ---- standalone GEMM kernel (layers 1 & 2, bf16 A): 16.9KB LDS, 4 blocks/CU ----
template<bool F32A>
__global__ __launch_bounds__(256,4) void k_gemm_bn(const void* __restrict__ Ap,
    const unsigned short* __restrict__ Wt, const float* __restrict__ bias,
    unsigned short* __restrict__ Zb, float* __restrict__ stats, int N){
  __shared__ __align__(16) char smem[16896];
  gemm_bn_body<F32A>(Ap, Wt, bias, Zb, stats, N, blockIdx.x, smem);
}

// ---- packed INTERLEAVED: gemm1 (GB blocks, f32 A) + place (GF blocks) ----
// bid%kk==kk-1 -> place (idx bid/kk); else gemm. Interleaving keeps both types
// co-resident (round-5 lesson: concatenation serializes). place order-insensitive.
__global__ __launch_bounds__(256,3) void k_g1pl(const float* __restrict__ x,
    const unsigned short* __restrict__ Wt, const float* __restrict__ bias,
    unsigned short* __restrict__ Zb, float* __restrict__ stats, int N, int GB,
    const int* __restrict__ row, const int* __restrict__ col,
    const float* __restrict__ ew, int E, int* __restrict__ cur,
    const float* __restrict__ dnorm, float2* __restrict__ pairs, int GF, int kk){
  __shared__ __align__(16) char smem[16896];
  int bid=blockIdx.x;
  int g=bid/kk, r=bid-g*kk;
  if(r==kk-1 && g<GF){
    place_body(row, col, ew, E, cur, dnorm, pairs, g);
  }else{
    int bfb = (g<GF)? g : GF;
    gemm_bn_body<true>(x, Wt, bias, Zb, stats, N, bid-bfb, smem);
  }
}

// ---------------- apply: BN finalize (in-block) + scale/shift + ReLU + residual ----------------
// 16 B/lane (8 ch). BNRES: residual operand is raw z0 -> apply stage-0 BN+ReLU inline
// (h0 never materialized). smi[0:256)=this stage scale/shift, smi[256:512)=residual's.
template<bool OUTF32, bool BNRES>
__global__ __launch_bounds__(256) void k_apply(const unsigned short* __restrict__ Zb,
    const float* __restrict__ stats, const float* __restrict__ gamma,
    const float* __restrict__ beta, float invN,
    const unsigned short* __restrict__ res,
    const float* __restrict__ rstats, const float* __restrict__ rgamma,
    const float* __restrict__ rbeta,
    float* __restrict__ outf, unsigned short* __restrict__ outb, int n16){
  __shared__ float smi[512];
  int t=threadIdx.x;
  if(t<128){
    float mean=stats[t]*invN;
    float var=stats[128+t]*invN - mean*mean;
    float sc=rsqrtf(var+EPS)*gamma[t];
    smi[t]=sc; smi[128+t]=beta[t]-mean*sc;
    if(BNRES){
      float rm=rstats[t]*invN;
      float rv=rstats[128+t]*invN - rm*rm;
      float rs=rsqrtf(rv+EPS)*rgamma[t];
      smi[256+t]=rs; smi[384+t]=rbeta[t]-rm*rs;
    }
  }
  __syncthreads();
  int i=blockIdx.x*256+t;
  if(i>=n16) return;
  int c=(i&15)*8;
  uint4 zu=((const uint4*)Zb)[i];
  float z[8]={bflo(zu.x),bfhi(zu.x),bflo(zu.y),bfhi(zu.y),
              bflo(zu.z),bfhi(zu.z),bflo(zu.w),bfhi(zu.w)};
  float o[8];
  #pragma unroll
  for(int k=0;k<8;k++) o[k]=fmaxf(fmaf(z[k],smi[c+k],smi[128+c+k]),0.f);
  if(res){
    uint4 ru=((const uint4*)res)[i];
    float r[8]={bflo(ru.x),bfhi(ru.x),bflo(ru.y),bfhi(ru.y),
                bflo(ru.z),bfhi(ru.z),bflo(ru.w),bfhi(ru.w)};
    if(BNRES){
      #pragma unroll
      for(int k=0;k<8;k++) r[k]=fmaxf(fmaf(r[k],smi[256+c+k],smi[384+c+k]),0.f);
    }
    #pragma unroll
    for(int k=0;k<8;k++) o[k]+=r[k];
  }
  if(OUTF32){
    float4 oa={o[0],o[1],o[2],o[3]}, ob={o[4],o[5],o[6],o[7]};
    ((float4*)outf)[2*i]  =oa;
    ((float4*)outf)[2*i+1]=ob;
  }else{
    uint4 pk;
    pk.x=pack_bf16(o[0],o[1]); pk.y=pack_bf16(o[2],o[3]);
    pk.z=pack_bf16(o[4],o[5]); pk.w=pack_bf16(o[6],o[7]);
    ((uint4*)outb)[i]=pk;
  }
}

extern "C" void kernel_launch(void* const* d_in, const int* in_sizes, int n_in,
                              void* d_out, int out_size, void* d_ws, size_t ws_size,
                              hipStream_t stream){
  const float* x      = (const float*)d_in[0];
  const int*   ei     = (const int*)  d_in[1];
  const float* ew     = (const float*)d_in[2];
  const float* fc_w   = (const float*)d_in[3];
  const float* fc_b   = (const float*)d_in[4];
  const float* conv_w = (const float*)d_in[5];
  const float* conv_b = (const float*)d_in[6];
  const float* gamma  = (const float*)d_in[7];
  const float* beta   = (const float*)d_in[8];
  float* out = (float*)d_out;

  int N = in_sizes[0]/H;
  int E = in_sizes[2];
  const int* row = ei;
  const int* col = ei + E;
  int B = (N+NPB-1)/NPB;                 // buckets

  // workspace layout (~65 MB)
  size_t NH = (size_t)N*H;
  unsigned short* Wt   = (unsigned short*)d_ws;  // 3*17408 bf16 (pitch-136 WT)
  unsigned short* zb   = Wt + 3*17408;           // N*H bf16: z0, then h1
  unsigned short* hbuf = zb + NH;                // N*H bf16: agg / z1 / z2
  float2* pairs  = (float2*)(hbuf + NH);         // E CSR records (val = ew*dnorm[row])
  float*  stats  = (float*)(pairs + E);          // 3*256  } contiguous with deg for
  int*    deg    = (int*)(stats + 768);          // N      } single memset
  int*    cur    = deg + N;                      // N
  float*  dnorm  = (float*)(cur + N);            // N
  int*    rowptr = (int*)(dnorm + N);            // N+1
  int*    btot   = rowptr + N + 1;               // B
  int*    bbase  = btot + B;                     // B+1

  hipMemsetAsync(stats, 0, sizeof(float)*768 + sizeof(int)*N, stream);

  int gE4k = (E+4095)/4096;
  int GB=(N+127)/128;

  // packed: wconv (192) | degcount (gE4k)
  k_wb<<<192+gE4k,256,0,stream>>>(fc_w, conv_w, Wt, 192, col, E, deg);
  k_btot<<<B,256,0,stream>>>(deg, N, btot);
  k_bscan<<<1,512,0,stream>>>(btot, B, E, bbase);
  k_p2a<<<B,256,0,stream>>>(deg, bbase, N, E, dnorm, rowptr, cur);
  // packed interleaved: gemm1 z0 = x@fc_w+fc_b (GB blocks) + place (gE4k blocks)
  {
    int GT=GB+gE4k, kk=GT/gE4k;
    k_g1pl<<<GT,256,0,stream>>>(x, Wt, fc_b, zb, stats, N, GB,
                                row, col, ew, E, cur, dnorm, pairs, gE4k, kk);
  }

  int gApply=((N*16)+255)/256;
  int gSpmm=(N+3)/4;
  float invN=1.f/(float)N;

  // layer 0: agg = A_hat @ relu(bn0(z0))  [BN0 inline in gather]  -> hbuf
  k_spmm_bf<true><<<gSpmm,256,0,stream>>>(pairs,rowptr,dnorm, zb, hbuf, N,
                                          stats, gamma, beta, invN);
  k_gemm_bn<false><<<GB,256,0,stream>>>(hbuf, Wt+17408, conv_b, hbuf, stats+256, N);
  // h1 = relu(bn1(z1)) + relu(bn0(z0))  -> zb (in-place over z0)
  k_apply<false,true><<<gApply,256,0,stream>>>(hbuf, stats+256, gamma+H, beta+H, invN,
                                               zb, stats, gamma, beta,
                                               nullptr, zb, N*16);

  // layer 1: out = relu(bn2(agg(h1) @ W1 + b1)) + h1 -> fp32 d_out
  k_spmm_bf<false><<<gSpmm,256,0,stream>>>(pairs,rowptr,dnorm, zb, hbuf, N,
                                           nullptr, nullptr, nullptr, 0.f);
  k_gemm_bn<false><<<GB,256,0,stream>>>(hbuf, Wt+2*17408, conv_b+H, hbuf, stats+512, N);
  k_apply<true,false><<<gApply,256,0,stream>>>(hbuf, stats+512, gamma+2*H, beta+2*H, invN,
                                               zb, nullptr, nullptr, nullptr,
                                               out, nullptr, N*16);
}

// Round 10
// 460.155 us; speedup vs baseline: 1.1892x; 1.1892x over previous
//
#include <hip/hip_runtime.h>

#define H 128
#define EPS 1e-5f
#define NPB 256      // nodes per bucket (pow2); bucket = node >> 8

typedef __attribute__((ext_vector_type(8))) short bf16x8;
typedef __attribute__((ext_vector_type(4))) float f32x4;

__device__ inline unsigned short f2bf(float f){
  unsigned int u=__float_as_uint(f);
  return (unsigned short)((u + 0x7FFFu + ((u>>16)&1u))>>16);
}
__device__ inline unsigned int pack_bf16(float a, float b){
  unsigned int ua=__float_as_uint(a), ub=__float_as_uint(b);
  ua = (ua + 0x7FFFu + ((ua>>16)&1u)) >> 16;
  ub = (ub + 0x7FFFu + ((ub>>16)&1u)) & 0xFFFF0000u;
  return ua | ub;
}
__device__ inline float bflo(unsigned int u){ return __uint_as_float(u<<16); }
__device__ inline float bfhi(unsigned int u){ return __uint_as_float(u&0xFFFF0000u); }

// ============ CSR build via 2-level bucket sort (round-5 proven config) ============
// Round-8 lesson: random fine-grained scatter doubles HBM writes — bucket sort keeps
// the scatter in 32KB windows. Round-9 lesson: cooperative grid-sync fusion is unsafe
// under graph capture (stats race). Round-10: p2a+p2b FUSED bucket-locally; the
// cross-bucket dnorm[row] fold moves into spmm as a wave-uniform scalar load
// (pairs.y = raw ew). Saves the 2nd 13MB stg pass + per-edge dnorm gathers + 1 dispatch.

__device__ __forceinline__ void bcount_body(const int* __restrict__ col, int E,
                                            int* __restrict__ bcnt, int bid){
  __shared__ int h[512];
  int t=threadIdx.x;
  for(int i=t;i<512;i+=256) h[i]=0;
  __syncthreads();
  int e0=bid*4096, e1=min(e0+4096,E);
  for(int e=e0+t;e<e1;e+=256) atomicAdd(&h[((unsigned)col[e])>>8],1);
  __syncthreads();
  for(int i=t;i<512;i+=256) if(h[i]) atomicAdd(&bcnt[i],h[i]);
}

__device__ __forceinline__ void wconv_body(const float* __restrict__ W0,
    const float* __restrict__ W1, unsigned short* __restrict__ Wt, int bid){
  int m=bid>>6;
  int lin=((bid&63)<<8)+threadIdx.x;            // 0..16383
  const float* src = (m==0) ? W0 : (W1 + (size_t)(m-1)*16384);
  int k=lin>>7, c=lin&127;
  Wt[(size_t)m*17408 + c*136 + k] = f2bf(src[lin]);
}

__global__ __launch_bounds__(256) void k_wb(const float* __restrict__ W0,
    const float* __restrict__ W1, unsigned short* __restrict__ Wt, int GW,
    const int* __restrict__ col, int E, int* __restrict__ bcnt){
  int bid=blockIdx.x;
  if(bid<GW) wconv_body(W0,W1,Wt,bid);
  else       bcount_body(col,E,bcnt,bid-GW);
}

__global__ void k_bscan(const int* __restrict__ bcnt, int B, int E,
                        int* __restrict__ bbase, int* __restrict__ cursor){
  __shared__ int s[512];
  int t=threadIdx.x;
  int v=(t<B)?bcnt[t]:0;
  s[t]=v; __syncthreads();
  for(int off=1;off<512;off<<=1){ int u=(t>=off)?s[t-off]:0; __syncthreads(); s[t]+=u; __syncthreads(); }
  if(t<B){ bbase[t]=s[t]-v; cursor[t]=s[t]-v; }
  if(t==0) bbase[B]=E;
}

__device__ __forceinline__ void bfill_body(const int* __restrict__ row, const int* __restrict__ col,
    const float* __restrict__ ew, int E, int* __restrict__ cursor, uint2* __restrict__ stg,
    int bid, char* smem){
  int* h  =(int*)smem;
  int* ofs=h+512;
  int t=threadIdx.x;
  for(int i=t;i<512;i+=256) h[i]=0;
  __syncthreads();
  int e0=bid*4096, e1=min(e0+4096,E);
  for(int e=e0+t;e<e1;e+=256) atomicAdd(&h[((unsigned)col[e])>>8],1);
  __syncthreads();
  for(int i=t;i<512;i+=256) ofs[i] = h[i] ? atomicAdd(&cursor[i],h[i]) : 0;
  __syncthreads();
  for(int i=t;i<512;i+=256) h[i]=0;
  __syncthreads();
  for(int e=e0+t;e<e1;e+=256){
    unsigned d=(unsigned)col[e];
    int b=d>>8;
    int lp=atomicAdd(&h[b],1);
    stg[ofs[b]+lp]=make_uint2(((d&255u)<<24)|(unsigned)row[e], __float_as_uint(ew[e]));
  }
}

// ---- fused per-bucket: histogram -> scan (dnorm/rowptr) -> placement ----
// The bucket's ~32KB stg slice stays L1/L2-hot between the two passes (old p2b's
// 13MB HBM re-read eliminated). pairs.y = raw ew; dnorm[row] folded in spmm.
__global__ __launch_bounds__(256) void k_p2ab(const uint2* __restrict__ stg,
    const int* __restrict__ bbase, int N, int E,
    float* __restrict__ dnorm, int* __restrict__ rowptr, float2* __restrict__ pairs){
  __shared__ int cnt[256];
  __shared__ int pre[256];
  __shared__ int cur[256];
  int b=blockIdx.x, t=threadIdx.x;
  cnt[t]=0; __syncthreads();
  int s0=bbase[b], s1=bbase[b+1];
  for(int p=s0+t;p<s1;p+=256) atomicAdd(&cnt[stg[p].x>>24],1);
  __syncthreads();
  int v=cnt[t];
  pre[t]=v; __syncthreads();
  for(int off=1;off<256;off<<=1){ int u=(t>=off)?pre[t-off]:0; __syncthreads(); pre[t]+=u; __syncthreads(); }
  int node=(b<<8)+t;
  int rp=s0+pre[t]-v;
  cur[t]=rp;
  if(node<N){
    dnorm[node]= v>0 ? rsqrtf((float)v) : 0.f;   // nan_to_num: deg==0 -> coefficient 0
    rowptr[node]=rp;
    if(node==N-1) rowptr[N]=E;
  }
  __syncthreads();
  for(int p=s0+t;p<s1;p+=256){
    uint2 rec=stg[p];                            // L1/L2-hot re-read
    int pos=atomicAdd(&cur[rec.x>>24],1);
    pairs[pos]=make_float2(__int_as_float((int)(rec.x&0xFFFFFFu)),
                           __uint_as_float(rec.y));
  }
}

// ---------------- SpMM bf16: wave/dest, 2 cols/lane, 16 gathers in flight ----------------
// Proven v8 body. All edge bookkeeping scalar: pairs via s_load, gather = SGPR base +
// lane offset. Round-10: pairs.y = raw ew; dnorm[row] applied here via wave-uniform
// scalar load (readfirstlane-forced) + one uniform VALU mul per edge.
// BN0 applies stage-0 BN+ReLU inline to each gathered value (gather source = raw z0).
template<bool BN0>
__global__ __launch_bounds__(256) void k_spmm_bf(const float2* __restrict__ pairs,
    const int* __restrict__ rowptr, const float* __restrict__ dnorm,
    const unsigned short* __restrict__ hb, unsigned short* __restrict__ zb, int N,
    const float* __restrict__ bnst, const float* __restrict__ gamma,
    const float* __restrict__ beta, float invN){
  int wid=(blockIdx.x*256+threadIdx.x)>>6;
  int lane=threadIdx.x&63;
  if(wid>=N) return;
  float sc0=0.f,sh0=0.f,sc1=0.f,sh1=0.f;
  if(BN0){
    int c0=lane<<1;
    float m0=bnst[c0]*invN,      m1=bnst[c0+1]*invN;
    float v0=bnst[128+c0]*invN-m0*m0, v1=bnst[129+c0]*invN-m1*m1;
    sc0=rsqrtf(v0+EPS)*gamma[c0];   sh0=beta[c0]-m0*sc0;
    sc1=rsqrtf(v1+EPS)*gamma[c0+1]; sh1=beta[c0+1]-m1*sc1;
  }
  int beg=__builtin_amdgcn_readfirstlane(rowptr[wid]);
  int end=__builtin_amdgcn_readfirstlane(rowptr[wid+1]);
  float ax=0.f, ay=0.f;
  int p=beg;
  for(; p+16<=end; p+=16){
    float2 pr[16]; unsigned int u[16]; float wv[16];
    int r[16];
    #pragma unroll
    for(int j=0;j<16;j++) pr[j]=pairs[p+j];
    #pragma unroll
    for(int j=0;j<16;j++) r[j]=__builtin_amdgcn_readfirstlane(__float_as_int(pr[j].x));
    #pragma unroll
    for(int j=0;j<16;j++) wv[j]=pr[j].y*dnorm[r[j]];
    #pragma unroll
    for(int j=0;j<16;j++)
      u[j]=*(const unsigned int*)(hb + (((size_t)r[j])<<7) + (lane<<1));
    #pragma unroll
    for(int j=0;j<16;j++){
      float f0=bflo(u[j]), f1=bfhi(u[j]);
      if(BN0){ f0=fmaxf(fmaf(f0,sc0,sh0),0.f); f1=fmaxf(fmaf(f1,sc1,sh1),0.f); }
      ax=fmaf(wv[j],f0,ax); ay=fmaf(wv[j],f1,ay);
    }
  }
  for(; p+4<=end; p+=4){
    float2 pr[4]; unsigned int u[4]; float wv[4];
    int r[4];
    #pragma unroll
    for(int j=0;j<4;j++) pr[j]=pairs[p+j];
    #pragma unroll
    for(int j=0;j<4;j++) r[j]=__builtin_amdgcn_readfirstlane(__float_as_int(pr[j].x));
    #pragma unroll
    for(int j=0;j<4;j++) wv[j]=pr[j].y*dnorm[r[j]];
    #pragma unroll
    for(int j=0;j<4;j++)
      u[j]=*(const unsigned int*)(hb + (((size_t)r[j])<<7) + (lane<<1));
    #pragma unroll
    for(int j=0;j<4;j++){
      float f0=bflo(u[j]), f1=bfhi(u[j]);
      if(BN0){ f0=fmaxf(fmaf(f0,sc0,sh0),0.f); f1=fmaxf(fmaf(f1,sc1,sh1),0.f); }
      ax=fmaf(wv[j],f0,ax); ay=fmaf(wv[j],f1,ay);
    }
  }
  for(; p<end; ++p){
    float2 pr=pairs[p];
    int r=__builtin_amdgcn_readfirstlane(__float_as_int(pr.x));
    float wv=pr.y*dnorm[r];
    unsigned int u=*(const unsigned int*)(hb + (((size_t)r)<<7) + (lane<<1));
    float f0=bflo(u), f1=bfhi(u);
    if(BN0){ f0=fmaxf(fmaf(f0,sc0,sh0),0.f); f1=fmaxf(fmaf(f1,sc1,sh1),0.f); }
    ax=fmaf(wv,f0,ax); ay=fmaf(wv,f1,ay);
  }
  float dn=dnorm[wid];
  *(unsigned int*)(zb + ((size_t)wid<<7) + (lane<<1)) = pack_bf16(ax*dn, ay*dn);
}

// ---------------- MFMA GEMM body (128 rows/block, LDS W-staging, round-5 proven) ----------------
template<bool F32A>
__device__ __forceinline__ void gemm_bn_body(const void* __restrict__ Ap,
    const unsigned short* __restrict__ Wt, const float* __restrict__ bias,
    unsigned short* __restrict__ Zb, float* __restrict__ stats, int N,
    int bid, char* smem){
  unsigned short* sWT=(unsigned short*)smem;              // 34816 B
  int t=threadIdx.x;

  {
    const uint4* gw=(const uint4*)Wt;                     // 2176 x 16B
    uint4* sw=(uint4*)sWT;
    #pragma unroll
    for(int it=0; it<8; it++) sw[t + it*256] = gw[t + it*256];
    if(t<128) sw[2048+t]=gw[2048+t];
  }
  __syncthreads();

  int w=t>>6, lane=t&63, n=lane&15, quad=lane>>4;
  int r0w = bid*128 + w*32;

  f32x4 acc[8][2];
  #pragma unroll
  for(int nt=0;nt<8;nt++)
    #pragma unroll
    for(int rt=0;rt<2;rt++){ f32x4 z4={0.f,0.f,0.f,0.f}; acc[nt][rt]=z4; }

  #pragma unroll
  for(int ks=0; ks<4; ks++){
    int k0 = ks*32 + quad*8;
    bf16x8 a[2];
    #pragma unroll
    for(int rt=0;rt<2;rt++){
      int r = r0w + rt*16 + n;
      bf16x8 af={0,0,0,0,0,0,0,0};
      if(r<N){
        if(F32A){
          const float* Af=(const float*)Ap;
          float4 u0=*(const float4*)&Af[(size_t)r*128 + k0];
          float4 u1=*(const float4*)&Af[(size_t)r*128 + k0 + 4];
          af[0]=(short)f2bf(u0.x); af[1]=(short)f2bf(u0.y);
          af[2]=(short)f2bf(u0.z); af[3]=(short)f2bf(u0.w);
          af[4]=(short)f2bf(u1.x); af[5]=(short)f2bf(u1.y);
          af[6]=(short)f2bf(u1.z); af[7]=(short)f2bf(u1.w);
        }else{
          af = *(const bf16x8*)((const unsigned short*)Ap + (size_t)r*128 + k0);
        }
      }
      a[rt]=af;
    }
    #pragma unroll
    for(int nt=0;nt<8;nt++){
      bf16x8 b = *(const bf16x8*)&sWT[(nt*16+n)*136 + k0];
      #pragma unroll
      for(int rt=0;rt<2;rt++)
        acc[nt][rt]=__builtin_amdgcn_mfma_f32_16x16x32_bf16(a[rt], b, acc[nt][rt], 0,0,0);
    }
  }

  __syncthreads();                        // reuse smem for stats partials
  float* sS=(float*)smem;                 // [16][132]
  float* sQ=sS + 16*132;                  // [16][132]
  #pragma unroll
  for(int nt=0;nt<8;nt++){
    int c=nt*16+n;
    float bc=bias[c];
    float s=0.f,q=0.f;
    #pragma unroll
    for(int rt=0;rt<2;rt++){
      #pragma unroll
      for(int i=0;i<4;i++){
        int r=r0w + rt*16 + quad*4 + i;
        if(r<N){
          float z=acc[nt][rt][i]+bc;
          Zb[(size_t)r*128+c]=f2bf(z);
          s+=z; q+=z*z;
        }
      }
    }
    sS[(w*4+quad)*132+c]=s;
    sQ[(w*4+quad)*132+c]=q;
  }
  __syncthreads();
  if(t<128){
    float s=0.f,q=0.f;
    #pragma unroll
    for(int g=0;g<16;g++){ s+=sS[g*132+t]; q+=sQ[g*132+t]; }
    atomicAdd(&stats[t],s); atomicAdd(&stats[128+t],q);
  }
}

// ---- standalone GEMM kernel (layers 1 & 2, bf16 A) ----
template<bool F32A>
__global__ __launch_bounds__(256,3) void k_gemm_bn(const void* __restrict__ Ap,
    const unsigned short* __restrict__ Wt, const float* __restrict__ bias,
    unsigned short* __restrict__ Zb, float* __restrict__ stats, int N){
  __shared__ __align__(16) char smem[34816];
  gemm_bn_body<F32A>(Ap, Wt, bias, Zb, stats, N, blockIdx.x, smem);
}

// ---- packed: [gemm1 (GB blocks, f32 A) | bfill] — round-5 proven arrangement ----
__global__ __launch_bounds__(256,3) void k_g1bf(const float* __restrict__ x,
    const unsigned short* __restrict__ Wt, const float* __restrict__ bias,
    unsigned short* __restrict__ Zb, float* __restrict__ stats, int N, int GB,
    const int* __restrict__ row, const int* __restrict__ col,
    const float* __restrict__ ew, int E, int* __restrict__ cursor,
    uint2* __restrict__ stg){
  __shared__ __align__(16) char smem[34816];
  int bid=blockIdx.x;
  if(bid<GB) gemm_bn_body<true>(x, Wt, bias, Zb, stats, N, bid, smem);
  else       bfill_body(row, col, ew, E, cursor, stg, bid-GB, smem);
}

// ---------------- apply: BN finalize (in-block) + scale/shift + ReLU + residual ----------------
// 16 B/lane (8 ch). BNRES: residual operand is raw z0 -> apply stage-0 BN+ReLU inline
// (h0 never materialized). smi[0:256)=this stage scale/shift, smi[256:512)=residual's.
template<bool OUTF32, bool BNRES>
__global__ __launch_bounds__(256) void k_apply(const unsigned short* __restrict__ Zb,
    const float* __restrict__ stats, const float* __restrict__ gamma,
    const float* __restrict__ beta, float invN,
    const unsigned short* __restrict__ res,
    const float* __restrict__ rstats, const float* __restrict__ rgamma,
    const float* __restrict__ rbeta,
    float* __restrict__ outf, unsigned short* __restrict__ outb, int n16){
  __shared__ float smi[512];
  int t=threadIdx.x;
  if(t<128){
    float mean=stats[t]*invN;
    float var=stats[128+t]*invN - mean*mean;
    float sc=rsqrtf(var+EPS)*gamma[t];
    smi[t]=sc; smi[128+t]=beta[t]-mean*sc;
    if(BNRES){
      float rm=rstats[t]*invN;
      float rv=rstats[128+t]*invN - rm*rm;
      float rs=rsqrtf(rv+EPS)*rgamma[t];
      smi[256+t]=rs; smi[384+t]=rbeta[t]-rm*rs;
    }
  }
  __syncthreads();
  int i=blockIdx.x*256+t;
  if(i>=n16) return;
  int c=(i&15)*8;
  uint4 zu=((const uint4*)Zb)[i];
  float z[8]={bflo(zu.x),bfhi(zu.x),bflo(zu.y),bfhi(zu.y),
              bflo(zu.z),bfhi(zu.z),bflo(zu.w),bfhi(zu.w)};
  float o[8];
  #pragma unroll
  for(int k=0;k<8;k++) o[k]=fmaxf(fmaf(z[k],smi[c+k],smi[128+c+k]),0.f);
  if(res){
    uint4 ru=((const uint4*)res)[i];
    float r[8]={bflo(ru.x),bfhi(ru.x),bflo(ru.y),bfhi(ru.y),
                bflo(ru.z),bfhi(ru.z),bflo(ru.w),bfhi(ru.w)};
    if(BNRES){
      #pragma unroll
      for(int k=0;k<8;k++) r[k]=fmaxf(fmaf(r[k],smi[256+c+k],smi[384+c+k]),0.f);
    }
    #pragma unroll
    for(int k=0;k<8;k++) o[k]+=r[k];
  }
  if(OUTF32){
    float4 oa={o[0],o[1],o[2],o[3]}, ob={o[4],o[5],o[6],o[7]};
    ((float4*)outf)[2*i]  =oa;
    ((float4*)outf)[2*i+1]=ob;
  }else{
    uint4 pk;
    pk.x=pack_bf16(o[0],o[1]); pk.y=pack_bf16(o[2],o[3]);
    pk.z=pack_bf16(o[4],o[5]); pk.w=pack_bf16(o[6],o[7]);
    ((uint4*)outb)[i]=pk;
  }
}

extern "C" void kernel_launch(void* const* d_in, const int* in_sizes, int n_in,
                              void* d_out, int out_size, void* d_ws, size_t ws_size,
                              hipStream_t stream){
  const float* x      = (const float*)d_in[0];
  const int*   ei     = (const int*)  d_in[1];
  const float* ew     = (const float*)d_in[2];
  const float* fc_w   = (const float*)d_in[3];
  const float* fc_b   = (const float*)d_in[4];
  const float* conv_w = (const float*)d_in[5];
  const float* conv_b = (const float*)d_in[6];
  const float* gamma  = (const float*)d_in[7];
  const float* beta   = (const float*)d_in[8];
  float* out = (float*)d_out;

  int N = in_sizes[0]/H;
  int E = in_sizes[2];
  const int* row = ei;
  const int* col = ei + E;
  int B = (N+NPB-1)/NPB;                 // buckets

  // workspace layout (~78 MB)
  size_t NH = (size_t)N*H;
  unsigned short* Wt   = (unsigned short*)d_ws;  // 3*17408 bf16 (pitch-136 WT)
  unsigned short* zb   = Wt + 3*17408;           // N*H bf16: z0, then h1
  unsigned short* hbuf = zb + NH;                // N*H bf16: agg / z1 / z2
  uint2*  stg    = (uint2*)(hbuf + NH);          // E bucket-grouped records
  float2* pairs  = (float2*)(stg + E);           // E final CSR records (val = raw ew)
  float*  stats  = (float*)(pairs + E);          // 3*256   } contiguous for
  int*    bcnt   = (int*)(stats + 768);          // 512     } single memset
  int*    bbase  = bcnt + 512;                   // 513
  int*    cursor = bbase + 513;                  // 512
  float*  dnorm  = (float*)(cursor + 512);       // N
  int*    rowptr = (int*)(dnorm + N);            // N+1

  hipMemsetAsync(stats, 0, sizeof(float)*(768+512), stream);

  int gE4k = (E+4095)/4096;
  int GB=(N+127)/128;

  // packed: wconv (192) | bcount (gE4k)
  k_wb<<<192+gE4k,256,0,stream>>>(fc_w, conv_w, Wt, 192, col, E, bcnt);
  k_bscan<<<1,512,0,stream>>>(bcnt,B,E,bbase,cursor);
  // packed: gemm1 z0 = x@fc_w+fc_b (GB blocks) | bfill (gE4k)
  k_g1bf<<<GB+gE4k,256,0,stream>>>(x, Wt, fc_b, zb, stats, N, GB,
                                   row, col, ew, E, cursor, stg);
  // fused per-bucket: histogram -> rowptr/dnorm -> placement (stg slice L2-hot)
  k_p2ab<<<B,256,0,stream>>>(stg,bbase,N,E,dnorm,rowptr,pairs);

  int gApply=((N*16)+255)/256;
  int gSpmm=(N+3)/4;
  float invN=1.f/(float)N;

  // layer 0: agg = A_hat @ relu(bn0(z0))  [BN0 inline in gather]  -> hbuf
  k_spmm_bf<true><<<gSpmm,256,0,stream>>>(pairs,rowptr,dnorm, zb, hbuf, N,
                                          stats, gamma, beta, invN);
  k_gemm_bn<false><<<GB,256,0,stream>>>(hbuf, Wt+17408, conv_b, hbuf, stats+256, N);
  // h1 = relu(bn1(z1)) + relu(bn0(z0))  -> zb (in-place over z0)
  k_apply<false,true><<<gApply,256,0,stream>>>(hbuf, stats+256, gamma+H, beta+H, invN,
                                               zb, stats, gamma, beta,
                                               nullptr, zb, N*16);

  // layer 1: out = relu(bn2(agg(h1) @ W1 + b1)) + h1 -> fp32 d_out
  k_spmm_bf<false><<<gSpmm,256,0,stream>>>(pairs,rowptr,dnorm, zb, hbuf, N,
                                           nullptr, nullptr, nullptr, 0.f);
  k_gemm_bn<false><<<GB,256,0,stream>>>(hbuf, Wt+2*17408, conv_b+H, hbuf, stats+512, N);
  k_apply<true,false><<<gApply,256,0,stream>>>(hbuf, stats+512, gamma+2*H, beta+2*H, invN,
                                               zb, nullptr, nullptr, nullptr,
                                               out, nullptr, N*16);
}

// Round 11
// 434.861 us; speedup vs baseline: 1.2584x; 1.0582x over previous
//
#include <hip/hip_runtime.h>

#define H 128
#define EPS 1e-5f
#define NPB 256      // nodes per bucket (pow2); bucket = node >> 8

typedef __attribute__((ext_vector_type(8))) short bf16x8;
typedef __attribute__((ext_vector_type(4))) float f32x4;

__device__ inline unsigned short f2bf(float f){
  unsigned int u=__float_as_uint(f);
  return (unsigned short)((u + 0x7FFFu + ((u>>16)&1u))>>16);
}
__device__ inline unsigned int pack_bf16(float a, float b){
  unsigned int ua=__float_as_uint(a), ub=__float_as_uint(b);
  ua = (ua + 0x7FFFu + ((ua>>16)&1u)) >> 16;
  ub = (ub + 0x7FFFu + ((ub>>16)&1u)) & 0xFFFF0000u;
  return ua | ub;
}
__device__ inline float bflo(unsigned int u){ return __uint_as_float(u<<16); }
__device__ inline float bfhi(unsigned int u){ return __uint_as_float(u&0xFFFF0000u); }

// ============ CSR build via 2-level bucket sort, ATOMIC-FREE partition (round-11) ============
// Rounds 5-7: k_g1bf stuck at ~88us with all pipes idle regardless of gemm body -> the
// invariant was bfill's global cursor atomics (~184K atomicAdds on 512 words, ~360
// serialized round-trips each ~ 100us serial chain). Round-11: radix-partition scan --
// per-block histograms to a matrix (plain stores), column-scan gives each (block,bucket)
// an exact disjoint slot, bfill becomes single-pass with LDS-only atomics.
// Round-8 lesson: keep bucket-localized scatter. Round-10 lesson: pairs.y stays
// pre-multiplied by dnorm[row] (scalar dnorm loads in spmm regressed it).

// ---- bcount2: per-block LDS histogram -> cntm[bid][k] (plain stores) ----
__device__ __forceinline__ void bcount2_body(const int* __restrict__ col, int E,
                                             int* __restrict__ cntm, int bid){
  __shared__ int h[512];
  int t=threadIdx.x;
  for(int i=t;i<512;i+=256) h[i]=0;
  __syncthreads();
  int e0=bid*4096, e1=min(e0+4096,E);
  for(int e=e0+t;e<e1;e+=256) atomicAdd(&h[((unsigned)col[e])>>8],1);
  __syncthreads();
  for(int i=t;i<512;i+=256) cntm[bid*512+i]=h[i];
}

// ---- one-time W transpose+convert: Wt[m][c*136+k] = bf16(W_m[k][c]) ----
__device__ __forceinline__ void wconv_body(const float* __restrict__ W0,
    const float* __restrict__ W1, unsigned short* __restrict__ Wt, int bid){
  int m=bid>>6;
  int lin=((bid&63)<<8)+threadIdx.x;            // 0..16383
  const float* src = (m==0) ? W0 : (W1 + (size_t)(m-1)*16384);
  int k=lin>>7, c=lin&127;
  Wt[(size_t)m*17408 + c*136 + k] = f2bf(src[lin]);
}

// ---- packed: [wconv (GW blocks) | bcount2] ----
__global__ __launch_bounds__(256) void k_wb(const float* __restrict__ W0,
    const float* __restrict__ W1, unsigned short* __restrict__ Wt, int GW,
    const int* __restrict__ col, int E, int* __restrict__ cntm){
  int bid=blockIdx.x;
  if(bid<GW) wconv_body(W0,W1,Wt,bid);
  else       bcount2_body(col,E,cntm,bid-GW);
}

// ---- column scan: for bucket k, exclusive-prefix cntm[b][k] over blocks b ----
// grid = B buckets, 512 threads. Writes prefix back in-place; bucket total -> btot[k].
__global__ void k_colscan(int* __restrict__ cntm, int GF, int* __restrict__ btot){
  __shared__ int s[512];
  int k=blockIdx.x, t=threadIdx.x;
  int v=(t<GF)? cntm[t*512+k] : 0;
  s[t]=v; __syncthreads();
  for(int off=1;off<512;off<<=1){ int u=(t>=off)?s[t-off]:0; __syncthreads(); s[t]+=u; __syncthreads(); }
  if(t<GF) cntm[t*512+k]=s[t]-v;
  if(t==511) btot[k]=s[511];
}

// ---- exclusive scan of bucket totals (single block, B<=512) ----
__global__ void k_bscan(const int* __restrict__ btot, int B, int E,
                        int* __restrict__ bbase){
  __shared__ int s[512];
  int t=threadIdx.x;
  int v=(t<B)?btot[t]:0;
  s[t]=v; __syncthreads();
  for(int off=1;off<512;off<<=1){ int u=(t>=off)?s[t-off]:0; __syncthreads(); s[t]+=u; __syncthreads(); }
  if(t<B) bbase[t]=s[t]-v;
  if(t==0) bbase[B]=E;
}

// ---- bfill2: SINGLE pass, zero global atomics ----
// sofs[b] = bbase[b] + cntm[bid][b] (precomputed disjoint slot); lp via LDS atomic.
__device__ __forceinline__ void bfill2_body(const int* __restrict__ row,
    const int* __restrict__ col, const float* __restrict__ ew, int E, int B,
    const int* __restrict__ cntm, const int* __restrict__ bbase,
    uint2* __restrict__ stg, int bid, char* smem){
  int* h   =(int*)smem;
  int* sofs=h+512;
  int t=threadIdx.x;
  for(int i=t;i<512;i+=256){
    h[i]=0;
    sofs[i]=(i<B)? (bbase[i]+cntm[bid*512+i]) : 0;
  }
  __syncthreads();
  int e0=bid*4096, e1=min(e0+4096,E);
  for(int e=e0+t;e<e1;e+=256){
    unsigned d=(unsigned)col[e];
    int b=d>>8;
    int lp=atomicAdd(&h[b],1);                       // LDS-only
    stg[sofs[b]+lp]=make_uint2(((d&255u)<<24)|(unsigned)row[e], __float_as_uint(ew[e]));
  }
}

// ---- per-bucket: degree -> dnorm + rowptr (round-5 verbatim) ----
__global__ __launch_bounds__(256) void k_p2a(const uint2* __restrict__ stg, const int* __restrict__ bbase,
    int N, int E, float* __restrict__ dnorm, int* __restrict__ rowptr){
  __shared__ int cnt[256];
  __shared__ int pre[256];
  int b=blockIdx.x, t=threadIdx.x;
  cnt[t]=0; __syncthreads();
  int s0=bbase[b], s1=bbase[b+1];
  for(int p=s0+t;p<s1;p+=256) atomicAdd(&cnt[stg[p].x>>24],1);
  __syncthreads();
  int v=cnt[t];
  pre[t]=v; __syncthreads();
  for(int off=1;off<256;off<<=1){ int u=(t>=off)?pre[t-off]:0; __syncthreads(); pre[t]+=u; __syncthreads(); }
  int node=(b<<8)+t;
  if(node<N){
    dnorm[node]= v>0 ? rsqrtf((float)v) : 0.f;   // nan_to_num: deg==0 -> coefficient 0
    rowptr[node]=s0+pre[t]-v;
    if(node==N-1) rowptr[N]=E;
  }
}

// ---- per-bucket: place records -> pairs, folding dnorm[row] (round-5 verbatim) ----
__global__ __launch_bounds__(256) void k_p2b(const uint2* __restrict__ stg, const int* __restrict__ bbase,
    int N, const int* __restrict__ rowptr, const float* __restrict__ dnorm,
    float2* __restrict__ pairs){
  __shared__ int cur[256];
  int b=blockIdx.x, t=threadIdx.x;
  int node=(b<<8)+t;
  cur[t]=(node<N)?rowptr[node]:0;
  __syncthreads();
  int s0=bbase[b], s1=bbase[b+1];
  for(int p=s0+t;p<s1;p+=256){
    uint2 rec=stg[p];
    int r=(int)(rec.x&0xFFFFFFu);
    int pos=atomicAdd(&cur[rec.x>>24],1);
    pairs[pos]=make_float2(__int_as_float(r), __uint_as_float(rec.y)*dnorm[r]);
  }
}

// ---------------- SpMM bf16: wave/dest, 2 cols/lane, 16 gathers in flight ----------------
// Proven v8 body (60.6us — do not touch). Edge bookkeeping fully scalar: pairs via
// s_load, gather = SGPR base + lane offset, weight (pre-multiplied by dnorm[row]) is an
// SGPR fma operand. v10/v11/r10 lessons: any per-lane or scalar-load addition here loses.
template<bool BN0>
__global__ __launch_bounds__(256) void k_spmm_bf(const float2* __restrict__ pairs,
    const int* __restrict__ rowptr, const float* __restrict__ dnorm,
    const unsigned short* __restrict__ hb, unsigned short* __restrict__ zb, int N,
    const float* __restrict__ bnst, const float* __restrict__ gamma,
    const float* __restrict__ beta, float invN){
  int wid=(blockIdx.x*256+threadIdx.x)>>6;
  int lane=threadIdx.x&63;
  if(wid>=N) return;
  float sc0=0.f,sh0=0.f,sc1=0.f,sh1=0.f;
  if(BN0){
    int c0=lane<<1;
    float m0=bnst[c0]*invN,      m1=bnst[c0+1]*invN;
    float v0=bnst[128+c0]*invN-m0*m0, v1=bnst[129+c0]*invN-m1*m1;
    sc0=rsqrtf(v0+EPS)*gamma[c0];   sh0=beta[c0]-m0*sc0;
    sc1=rsqrtf(v1+EPS)*gamma[c0+1]; sh1=beta[c0+1]-m1*sc1;
  }
  int beg=__builtin_amdgcn_readfirstlane(rowptr[wid]);
  int end=__builtin_amdgcn_readfirstlane(rowptr[wid+1]);
  float ax=0.f, ay=0.f;
  int p=beg;
  for(; p+16<=end; p+=16){
    float2 pr[16]; unsigned int u[16];
    #pragma unroll
    for(int j=0;j<16;j++) pr[j]=pairs[p+j];
    #pragma unroll
    for(int j=0;j<16;j++)
      u[j]=*(const unsigned int*)(hb + (((size_t)__float_as_int(pr[j].x))<<7) + (lane<<1));
    #pragma unroll
    for(int j=0;j<16;j++){
      float f0=bflo(u[j]), f1=bfhi(u[j]);
      if(BN0){ f0=fmaxf(fmaf(f0,sc0,sh0),0.f); f1=fmaxf(fmaf(f1,sc1,sh1),0.f); }
      ax=fmaf(pr[j].y,f0,ax); ay=fmaf(pr[j].y,f1,ay);
    }
  }
  for(; p+4<=end; p+=4){
    float2 pr[4]; unsigned int u[4];
    #pragma unroll
    for(int j=0;j<4;j++) pr[j]=pairs[p+j];
    #pragma unroll
    for(int j=0;j<4;j++)
      u[j]=*(const unsigned int*)(hb + (((size_t)__float_as_int(pr[j].x))<<7) + (lane<<1));
    #pragma unroll
    for(int j=0;j<4;j++){
      float f0=bflo(u[j]), f1=bfhi(u[j]);
      if(BN0){ f0=fmaxf(fmaf(f0,sc0,sh0),0.f); f1=fmaxf(fmaf(f1,sc1,sh1),0.f); }
      ax=fmaf(pr[j].y,f0,ax); ay=fmaf(pr[j].y,f1,ay);
    }
  }
  for(; p<end; ++p){
    float2 pr=pairs[p];
    unsigned int u=*(const unsigned int*)(hb + (((size_t)__float_as_int(pr.x))<<7) + (lane<<1));
    float f0=bflo(u), f1=bfhi(u);
    if(BN0){ f0=fmaxf(fmaf(f0,sc0,sh0),0.f); f1=fmaxf(fmaf(f1,sc1,sh1),0.f); }
    ax=fmaf(pr.y,f0,ax); ay=fmaf(pr.y,f1,ay);
  }
  float dn=dnorm[wid];
  *(unsigned int*)(zb + ((size_t)wid<<7) + (lane<<1)) = pack_bf16(ax*dn, ay*dn);
}

// ---------------- MFMA GEMM body (128 rows/block, LDS W-staging, round-5 proven) ----------------
template<bool F32A>
__device__ __forceinline__ void gemm_bn_body(const void* __restrict__ Ap,
    const unsigned short* __restrict__ Wt, const float* __restrict__ bias,
    unsigned short* __restrict__ Zb, float* __restrict__ stats, int N,
    int bid, char* smem){
  unsigned short* sWT=(unsigned short*)smem;              // 34816 B
  int t=threadIdx.x;

  {
    const uint4* gw=(const uint4*)Wt;                     // 2176 x 16B
    uint4* sw=(uint4*)sWT;
    #pragma unroll
    for(int it=0; it<8; it++) sw[t + it*256] = gw[t + it*256];
    if(t<128) sw[2048+t]=gw[2048+t];
  }
  __syncthreads();

  int w=t>>6, lane=t&63, n=lane&15, quad=lane>>4;
  int r0w = bid*128 + w*32;

  f32x4 acc[8][2];
  #pragma unroll
  for(int nt=0;nt<8;nt++)
    #pragma unroll
    for(int rt=0;rt<2;rt++){ f32x4 z4={0.f,0.f,0.f,0.f}; acc[nt][rt]=z4; }

  #pragma unroll
  for(int ks=0; ks<4; ks++){
    int k0 = ks*32 + quad*8;
    bf16x8 a[2];
    #pragma unroll
    for(int rt=0;rt<2;rt++){
      int r = r0w + rt*16 + n;
      bf16x8 af={0,0,0,0,0,0,0,0};
      if(r<N){
        if(F32A){
          const float* Af=(const float*)Ap;
          float4 u0=*(const float4*)&Af[(size_t)r*128 + k0];
          float4 u1=*(const float4*)&Af[(size_t)r*128 + k0 + 4];
          af[0]=(short)f2bf(u0.x); af[1]=(short)f2bf(u0.y);
          af[2]=(short)f2bf(u0.z); af[3]=(short)f2bf(u0.w);
          af[4]=(short)f2bf(u1.x); af[5]=(short)f2bf(u1.y);
          af[6]=(short)f2bf(u1.z); af[7]=(short)f2bf(u1.w);
        }else{
          af = *(const bf16x8*)((const unsigned short*)Ap + (size_t)r*128 + k0);
        }
      }
      a[rt]=af;
    }
    #pragma unroll
    for(int nt=0;nt<8;nt++){
      bf16x8 b = *(const bf16x8*)&sWT[(nt*16+n)*136 + k0];
      #pragma unroll
      for(int rt=0;rt<2;rt++)
        acc[nt][rt]=__builtin_amdgcn_mfma_f32_16x16x32_bf16(a[rt], b, acc[nt][rt], 0,0,0);
    }
  }

  __syncthreads();                        // reuse smem for stats partials
  float* sS=(float*)smem;                 // [16][132]
  float* sQ=sS + 16*132;                  // [16][132]
  #pragma unroll
  for(int nt=0;nt<8;nt++){
    int c=nt*16+n;
    float bc=bias[c];
    float s=0.f,q=0.f;
    #pragma unroll
    for(int rt=0;rt<2;rt++){
      #pragma unroll
      for(int i=0;i<4;i++){
        int r=r0w + rt*16 + quad*4 + i;
        if(r<N){
          float z=acc[nt][rt][i]+bc;
          Zb[(size_t)r*128+c]=f2bf(z);
          s+=z; q+=z*z;
        }
      }
    }
    sS[(w*4+quad)*132+c]=s;
    sQ[(w*4+quad)*132+c]=q;
  }
  __syncthreads();
  if(t<128){
    float s=0.f,q=0.f;
    #pragma unroll
    for(int g=0;g<16;g++){ s+=sS[g*132+t]; q+=sQ[g*132+t]; }
    atomicAdd(&stats[t],s); atomicAdd(&stats[128+t],q);
  }
}

// ---- standalone GEMM kernel (layers 1 & 2, bf16 A) ----
template<bool F32A>
__global__ __launch_bounds__(256,3) void k_gemm_bn(const void* __restrict__ Ap,
    const unsigned short* __restrict__ Wt, const float* __restrict__ bias,
    unsigned short* __restrict__ Zb, float* __restrict__ stats, int N){
  __shared__ __align__(16) char smem[34816];
  gemm_bn_body<F32A>(Ap, Wt, bias, Zb, stats, N, blockIdx.x, smem);
}

// ---- packed: [gemm1 (GB blocks, f32 A) | bfill2] ----
__global__ __launch_bounds__(256,3) void k_g1bf(const float* __restrict__ x,
    const unsigned short* __restrict__ Wt, const float* __restrict__ bias,
    unsigned short* __restrict__ Zb, float* __restrict__ stats, int N, int GB,
    const int* __restrict__ row, const int* __restrict__ col,
    const float* __restrict__ ew, int E, int B,
    const int* __restrict__ cntm, const int* __restrict__ bbase,
    uint2* __restrict__ stg){
  __shared__ __align__(16) char smem[34816];
  int bid=blockIdx.x;
  if(bid<GB) gemm_bn_body<true>(x, Wt, bias, Zb, stats, N, bid, smem);
  else       bfill2_body(row, col, ew, E, B, cntm, bbase, stg, bid-GB, smem);
}

// ---------------- apply: BN finalize + scale/shift + ReLU + residual (round-5) ----------------
template<bool OUTF32, bool BNRES>
__global__ __launch_bounds__(256) void k_apply(const unsigned short* __restrict__ Zb,
    const float* __restrict__ stats, const float* __restrict__ gamma,
    const float* __restrict__ beta, float invN,
    const unsigned short* __restrict__ res,
    const float* __restrict__ rstats, const float* __restrict__ rgamma,
    const float* __restrict__ rbeta,
    float* __restrict__ outf, unsigned short* __restrict__ outb, int n16){
  __shared__ float smi[512];
  int t=threadIdx.x;
  if(t<128){
    float mean=stats[t]*invN;
    float var=stats[128+t]*invN - mean*mean;
    float sc=rsqrtf(var+EPS)*gamma[t];
    smi[t]=sc; smi[128+t]=beta[t]-mean*sc;
    if(BNRES){
      float rm=rstats[t]*invN;
      float rv=rstats[128+t]*invN - rm*rm;
      float rs=rsqrtf(rv+EPS)*rgamma[t];
      smi[256+t]=rs; smi[384+t]=rbeta[t]-rm*rs;
    }
  }
  __syncthreads();
  int i=blockIdx.x*256+t;
  if(i>=n16) return;
  int c=(i&15)*8;
  uint4 zu=((const uint4*)Zb)[i];
  float z[8]={bflo(zu.x),bfhi(zu.x),bflo(zu.y),bfhi(zu.y),
              bflo(zu.z),bfhi(zu.z),bflo(zu.w),bfhi(zu.w)};
  float o[8];
  #pragma unroll
  for(int k=0;k<8;k++) o[k]=fmaxf(fmaf(z[k],smi[c+k],smi[128+c+k]),0.f);
  if(res){
    uint4 ru=((const uint4*)res)[i];
    float r[8]={bflo(ru.x),bfhi(ru.x),bflo(ru.y),bfhi(ru.y),
                bflo(ru.z),bfhi(ru.z),bflo(ru.w),bfhi(ru.w)};
    if(BNRES){
      #pragma unroll
      for(int k=0;k<8;k++) r[k]=fmaxf(fmaf(r[k],smi[256+c+k],smi[384+c+k]),0.f);
    }
    #pragma unroll
    for(int k=0;k<8;k++) o[k]+=r[k];
  }
  if(OUTF32){
    float4 oa={o[0],o[1],o[2],o[3]}, ob={o[4],o[5],o[6],o[7]};
    ((float4*)outf)[2*i]  =oa;
    ((float4*)outf)[2*i+1]=ob;
  }else{
    uint4 pk;
    pk.x=pack_bf16(o[0],o[1]); pk.y=pack_bf16(o[2],o[3]);
    pk.z=pack_bf16(o[4],o[5]); pk.w=pack_bf16(o[6],o[7]);
    ((uint4*)outb)[i]=pk;
  }
}

extern "C" void kernel_launch(void* const* d_in, const int* in_sizes, int n_in,
                              void* d_out, int out_size, void* d_ws, size_t ws_size,
                              hipStream_t stream){
  const float* x      = (const float*)d_in[0];
  const int*   ei     = (const int*)  d_in[1];
  const float* ew     = (const float*)d_in[2];
  const float* fc_w   = (const float*)d_in[3];
  const float* fc_b   = (const float*)d_in[4];
  const float* conv_w = (const float*)d_in[5];
  const float* conv_b = (const float*)d_in[6];
  const float* gamma  = (const float*)d_in[7];
  const float* beta   = (const float*)d_in[8];
  float* out = (float*)d_out;

  int N = in_sizes[0]/H;
  int E = in_sizes[2];
  const int* row = ei;
  const int* col = ei + E;
  int B = (N+NPB-1)/NPB;                 // buckets (<=512)
  int GF = (E+4095)/4096;                // bfill blocks (<=512)

  // workspace layout (~79 MB)
  size_t NH = (size_t)N*H;
  unsigned short* Wt   = (unsigned short*)d_ws;  // 3*17408 bf16 (pitch-136 WT)
  unsigned short* zb   = Wt + 3*17408;           // N*H bf16: z0, then h1
  unsigned short* hbuf = zb + NH;                // N*H bf16: agg / z1 / z2
  uint2*  stg    = (uint2*)(hbuf + NH);          // E bucket-grouped records
  float2* pairs  = (float2*)(stg + E);           // E final CSR records (val = ew*dnorm[row])
  float*  stats  = (float*)(pairs + E);          // 3*256 (memset)
  int*    btot   = (int*)(stats + 768);          // 512
  int*    bbase  = btot + 512;                   // 513
  float*  dnorm  = (float*)(bbase + 513);        // N
  int*    rowptr = (int*)(dnorm + N);            // N+1
  int*    cntm   = rowptr + N + 1;               // 512*512 partition matrix

  hipMemsetAsync(stats, 0, sizeof(float)*768, stream);

  int GB=(N+127)/128;

  // packed: wconv (192) | bcount2 (GF) — per-block histograms, no global atomics
  k_wb<<<192+GF,256,0,stream>>>(fc_w, conv_w, Wt, 192, col, E, cntm);
  k_colscan<<<B,512,0,stream>>>(cntm, GF, btot);
  k_bscan<<<1,512,0,stream>>>(btot, B, E, bbase);
  // packed: gemm1 z0 = x@fc_w+fc_b (GB blocks) | bfill2 (GF, single-pass, LDS-only atomics)
  k_g1bf<<<GB+GF,256,0,stream>>>(x, Wt, fc_b, zb, stats, N, GB,
                                 row, col, ew, E, B, cntm, bbase, stg);
  k_p2a<<<B,256,0,stream>>>(stg,bbase,N,E,dnorm,rowptr);
  k_p2b<<<B,256,0,stream>>>(stg,bbase,N,rowptr,dnorm,pairs);

  int gApply=((N*16)+255)/256;
  int gSpmm=(N+3)/4;
  float invN=1.f/(float)N;

  // layer 0: agg = A_hat @ relu(bn0(z0))  [BN0 inline in gather]  -> hbuf
  k_spmm_bf<true><<<gSpmm,256,0,stream>>>(pairs,rowptr,dnorm, zb, hbuf, N,
                                          stats, gamma, beta, invN);
  k_gemm_bn<false><<<GB,256,0,stream>>>(hbuf, Wt+17408, conv_b, hbuf, stats+256, N);
  // h1 = relu(bn1(z1)) + relu(bn0(z0))  -> zb (in-place over z0)
  k_apply<false,true><<<gApply,256,0,stream>>>(hbuf, stats+256, gamma+H, beta+H, invN,
                                               zb, stats, gamma, beta,
                                               nullptr, zb, N*16);

  // layer 1: out = relu(bn2(agg(h1) @ W1 + b1)) + h1 -> fp32 d_out
  k_spmm_bf<false><<<gSpmm,256,0,stream>>>(pairs,rowptr,dnorm, zb, hbuf, N,
                                           nullptr, nullptr, nullptr, 0.f);
  k_gemm_bn<false><<<GB,256,0,stream>>>(hbuf, Wt+2*17408, conv_b+H, hbuf, stats+512, N);
  k_apply<true,false><<<gApply,256,0,stream>>>(hbuf, stats+512, gamma+2*H, beta+2*H, invN,
                                               zb, nullptr, nullptr, nullptr,
                                               out, nullptr, N*16);
}

// Round 13
// 415.026 us; speedup vs baseline: 1.3185x; 1.0478x over previous
//
#include <hip/hip_runtime.h>

#define H 128
#define EPS 1e-5f
#define NPB 256      // nodes per bucket (pow2); bucket = node >> 8
#define SREP 8       // stats replicas (contention /8); round-12

typedef __attribute__((ext_vector_type(8))) short bf16x8;
typedef __attribute__((ext_vector_type(4))) float f32x4;

__device__ inline unsigned short f2bf(float f){
  unsigned int u=__float_as_uint(f);
  return (unsigned short)((u + 0x7FFFu + ((u>>16)&1u))>>16);
}
__device__ inline unsigned int pack_bf16(float a, float b){
  unsigned int ua=__float_as_uint(a), ub=__float_as_uint(b);
  ua = (ua + 0x7FFFu + ((ua>>16)&1u)) >> 16;
  ub = (ub + 0x7FFFu + ((ub>>16)&1u)) & 0xFFFF0000u;
  return ua | ub;
}
__device__ inline float bflo(unsigned int u){ return __uint_as_float(u<<16); }
__device__ inline float bfhi(unsigned int u){ return __uint_as_float(u&0xFFFF0000u); }

// ============ CSR build via 2-level bucket sort, ATOMIC-FREE partition (round-11) ============
// Round-11 confirmed: high-fan-in same-address global atomics cost ~10+us per 100K-atomic
// dispatch (bfill cursor atomics removal: k_g1bf 88->75us). Round-12 applies the same fix
// to the GEMM stats atomics (782 blocks x 256 words = ~390 serialized RTs/address, 3
// dispatches): 8-replica accumulators, consumers sum replicas.
// Round-8 lesson: keep bucket-localized scatter. Round-10 lesson: pairs.y stays
// pre-multiplied by dnorm[row].

// ---- bcount2: per-block LDS histogram -> cntm[bid][k] (plain stores) ----
__device__ __forceinline__ void bcount2_body(const int* __restrict__ col, int E,
                                             int* __restrict__ cntm, int bid){
  __shared__ int h[512];
  int t=threadIdx.x;
  for(int i=t;i<512;i+=256) h[i]=0;
  __syncthreads();
  int e0=bid*4096, e1=min(e0+4096,E);
  for(int e=e0+t;e<e1;e+=256) atomicAdd(&h[((unsigned)col[e])>>8],1);
  __syncthreads();
  for(int i=t;i<512;i+=256) cntm[bid*512+i]=h[i];
}

// ---- one-time W transpose+convert: Wt[m][c*136+k] = bf16(W_m[k][c]) ----
__device__ __forceinline__ void wconv_body(const float* __restrict__ W0,
    const float* __restrict__ W1, unsigned short* __restrict__ Wt, int bid){
  int m=bid>>6;
  int lin=((bid&63)<<8)+threadIdx.x;            // 0..16383
  const float* src = (m==0) ? W0 : (W1 + (size_t)(m-1)*16384);
  int k=lin>>7, c=lin&127;
  Wt[(size_t)m*17408 + c*136 + k] = f2bf(src[lin]);
}

// ---- packed: [wconv (GW blocks) | bcount2] ----
__global__ __launch_bounds__(256) void k_wb(const float* __restrict__ W0,
    const float* __restrict__ W1, unsigned short* __restrict__ Wt, int GW,
    const int* __restrict__ col, int E, int* __restrict__ cntm){
  int bid=blockIdx.x;
  if(bid<GW) wconv_body(W0,W1,Wt,bid);
  else       bcount2_body(col,E,cntm,bid-GW);
}

// ---- column scan: for bucket k, exclusive-prefix cntm[b][k] over blocks b ----
__global__ void k_colscan(int* __restrict__ cntm, int GF, int* __restrict__ btot){
  __shared__ int s[512];
  int k=blockIdx.x, t=threadIdx.x;
  int v=(t<GF)? cntm[t*512+k] : 0;
  s[t]=v; __syncthreads();
  for(int off=1;off<512;off<<=1){ int u=(t>=off)?s[t-off]:0; __syncthreads(); s[t]+=u; __syncthreads(); }
  if(t<GF) cntm[t*512+k]=s[t]-v;
  if(t==511) btot[k]=s[511];
}

// ---- exclusive scan of bucket totals (single block, B<=512) ----
__global__ void k_bscan(const int* __restrict__ btot, int B, int E,
                        int* __restrict__ bbase){
  __shared__ int s[512];
  int t=threadIdx.x;
  int v=(t<B)?btot[t]:0;
  s[t]=v; __syncthreads();
  for(int off=1;off<512;off<<=1){ int u=(t>=off)?s[t-off]:0; __syncthreads(); s[t]+=u; __syncthreads(); }
  if(t<B) bbase[t]=s[t]-v;
  if(t==0) bbase[B]=E;
}

// ---- bfill2: SINGLE pass, zero global atomics ----
__device__ __forceinline__ void bfill2_body(const int* __restrict__ row,
    const int* __restrict__ col, const float* __restrict__ ew, int E, int B,
    const int* __restrict__ cntm, const int* __restrict__ bbase,
    uint2* __restrict__ stg, int bid, char* smem){
  int* h   =(int*)smem;
  int* sofs=h+512;
  int t=threadIdx.x;
  for(int i=t;i<512;i+=256){
    h[i]=0;
    sofs[i]=(i<B)? (bbase[i]+cntm[bid*512+i]) : 0;
  }
  __syncthreads();
  int e0=bid*4096, e1=min(e0+4096,E);
  for(int e=e0+t;e<e1;e+=256){
    unsigned d=(unsigned)col[e];
    int b=d>>8;
    int lp=atomicAdd(&h[b],1);                       // LDS-only
    stg[sofs[b]+lp]=make_uint2(((d&255u)<<24)|(unsigned)row[e], __float_as_uint(ew[e]));
  }
}

// ---- per-bucket: degree -> dnorm + rowptr ----
__global__ __launch_bounds__(256) void k_p2a(const uint2* __restrict__ stg, const int* __restrict__ bbase,
    int N, int E, float* __restrict__ dnorm, int* __restrict__ rowptr){
  __shared__ int cnt[256];
  __shared__ int pre[256];
  int b=blockIdx.x, t=threadIdx.x;
  cnt[t]=0; __syncthreads();
  int s0=bbase[b], s1=bbase[b+1];
  for(int p=s0+t;p<s1;p+=256) atomicAdd(&cnt[stg[p].x>>24],1);
  __syncthreads();
  int v=cnt[t];
  pre[t]=v; __syncthreads();
  for(int off=1;off<256;off<<=1){ int u=(t>=off)?pre[t-off]:0; __syncthreads(); pre[t]+=u; __syncthreads(); }
  int node=(b<<8)+t;
  if(node<N){
    dnorm[node]= v>0 ? rsqrtf((float)v) : 0.f;   // nan_to_num: deg==0 -> coefficient 0
    rowptr[node]=s0+pre[t]-v;
    if(node==N-1) rowptr[N]=E;
  }
}

// ---- per-bucket: place records -> pairs, folding dnorm[row] ----
__global__ __launch_bounds__(256) void k_p2b(const uint2* __restrict__ stg, const int* __restrict__ bbase,
    int N, const int* __restrict__ rowptr, const float* __restrict__ dnorm,
    float2* __restrict__ pairs){
  __shared__ int cur[256];
  int b=blockIdx.x, t=threadIdx.x;
  int node=(b<<8)+t;
  cur[t]=(node<N)?rowptr[node]:0;
  __syncthreads();
  int s0=bbase[b], s1=bbase[b+1];
  for(int p=s0+t;p<s1;p+=256){
    uint2 rec=stg[p];
    int r=(int)(rec.x&0xFFFFFFu);
    int pos=atomicAdd(&cur[rec.x>>24],1);
    pairs[pos]=make_float2(__int_as_float(r), __uint_as_float(rec.y)*dnorm[r]);
  }
}

// ---------------- SpMM bf16: wave/dest, 2 cols/lane, 16 gathers in flight ----------------
// Proven v8 body (60.6us — do not touch). Edge bookkeeping fully scalar.
// BN0: stage-0 BN+ReLU inline; bnst points at 8-replica stats (summed at init).
template<bool BN0>
__global__ __launch_bounds__(256) void k_spmm_bf(const float2* __restrict__ pairs,
    const int* __restrict__ rowptr, const float* __restrict__ dnorm,
    const unsigned short* __restrict__ hb, unsigned short* __restrict__ zb, int N,
    const float* __restrict__ bnst, const float* __restrict__ gamma,
    const float* __restrict__ beta, float invN){
  int wid=(blockIdx.x*256+threadIdx.x)>>6;
  int lane=threadIdx.x&63;
  if(wid>=N) return;
  float sc0=0.f,sh0=0.f,sc1=0.f,sh1=0.f;
  if(BN0){
    int c0=lane<<1;
    float s0=0.f,s1v=0.f,q0=0.f,q1v=0.f;
    #pragma unroll
    for(int r2=0;r2<SREP;r2++){
      s0 +=bnst[r2*256+c0];     s1v+=bnst[r2*256+c0+1];
      q0 +=bnst[r2*256+128+c0]; q1v+=bnst[r2*256+129+c0];
    }
    float m0=s0*invN,           m1=s1v*invN;
    float v0=q0*invN-m0*m0,     v1=q1v*invN-m1*m1;
    sc0=rsqrtf(v0+EPS)*gamma[c0];   sh0=beta[c0]-m0*sc0;
    sc1=rsqrtf(v1+EPS)*gamma[c0+1]; sh1=beta[c0+1]-m1*sc1;
  }
  int beg=__builtin_amdgcn_readfirstlane(rowptr[wid]);
  int end=__builtin_amdgcn_readfirstlane(rowptr[wid+1]);
  float ax=0.f, ay=0.f;
  int p=beg;
  for(; p+16<=end; p+=16){
    float2 pr[16]; unsigned int u[16];
    #pragma unroll
    for(int j=0;j<16;j++) pr[j]=pairs[p+j];
    #pragma unroll
    for(int j=0;j<16;j++)
      u[j]=*(const unsigned int*)(hb + (((size_t)__float_as_int(pr[j].x))<<7) + (lane<<1));
    #pragma unroll
    for(int j=0;j<16;j++){
      float f0=bflo(u[j]), f1=bfhi(u[j]);
      if(BN0){ f0=fmaxf(fmaf(f0,sc0,sh0),0.f); f1=fmaxf(fmaf(f1,sc1,sh1),0.f); }
      ax=fmaf(pr[j].y,f0,ax); ay=fmaf(pr[j].y,f1,ay);
    }
  }
  for(; p+4<=end; p+=4){
    float2 pr[4]; unsigned int u[4];
    #pragma unroll
    for(int j=0;j<4;j++) pr[j]=pairs[p+j];
    #pragma unroll
    for(int j=0;j<4;j++)
      u[j]=*(const unsigned int*)(hb + (((size_t)__float_as_int(pr[j].x))<<7) + (lane<<1));
    #pragma unroll
    for(int j=0;j<4;j++){
      float f0=bflo(u[j]), f1=bfhi(u[j]);
      if(BN0){ f0=fmaxf(fmaf(f0,sc0,sh0),0.f); f1=fmaxf(fmaf(f1,sc1,sh1),0.f); }
      ax=fmaf(pr[j].y,f0,ax); ay=fmaf(pr[j].y,f1,ay);
    }
  }
  for(; p<end; ++p){
    float2 pr=pairs[p];
    unsigned int u=*(const unsigned int*)(hb + (((size_t)__float_as_int(pr.x))<<7) + (lane<<1));
    float f0=bflo(u), f1=bfhi(u);
    if(BN0){ f0=fmaxf(fmaf(f0,sc0,sh0),0.f); f1=fmaxf(fmaf(f1,sc1,sh1),0.f); }
    ax=fmaf(pr.y,f0,ax); ay=fmaf(pr.y,f1,ay);
  }
  float dn=dnorm[wid];
  *(unsigned int*)(zb + ((size_t)wid<<7) + (lane<<1)) = pack_bf16(ax*dn, ay*dn);
}

// ---------------- MFMA GEMM body (128 rows/block, LDS W-staging) ----------------
// Round-12: stats atomics go to replica (bid&7) — contention /8 (round-11 mechanism).
template<bool F32A>
__device__ __forceinline__ void gemm_bn_body(const void* __restrict__ Ap,
    const unsigned short* __restrict__ Wt, const float* __restrict__ bias,
    unsigned short* __restrict__ Zb, float* __restrict__ stats, int N,
    int bid, char* smem){
  unsigned short* sWT=(unsigned short*)smem;              // 34816 B
  int t=threadIdx.x;

  {
    const uint4* gw=(const uint4*)Wt;                     // 2176 x 16B
    uint4* sw=(uint4*)sWT;
    #pragma unroll
    for(int it=0; it<8; it++) sw[t + it*256] = gw[t + it*256];
    if(t<128) sw[2048+t]=gw[2048+t];
  }
  __syncthreads();

  int w=t>>6, lane=t&63, n=lane&15, quad=lane>>4;
  int r0w = bid*128 + w*32;

  f32x4 acc[8][2];
  #pragma unroll
  for(int nt=0;nt<8;nt++)
    #pragma unroll
    for(int rt=0;rt<2;rt++){ f32x4 z4={0.f,0.f,0.f,0.f}; acc[nt][rt]=z4; }

  #pragma unroll
  for(int ks=0; ks<4; ks++){
    int k0 = ks*32 + quad*8;
    bf16x8 a[2];
    #pragma unroll
    for(int rt=0;rt<2;rt++){
      int r = r0w + rt*16 + n;
      bf16x8 af={0,0,0,0,0,0,0,0};
      if(r<N){
        if(F32A){
          const float* Af=(const float*)Ap;
          float4 u0=*(const float4*)&Af[(size_t)r*128 + k0];
          float4 u1=*(const float4*)&Af[(size_t)r*128 + k0 + 4];
          af[0]=(short)f2bf(u0.x); af[1]=(short)f2bf(u0.y);
          af[2]=(short)f2bf(u0.z); af[3]=(short)f2bf(u0.w);
          af[4]=(short)f2bf(u1.x); af[5]=(short)f2bf(u1.y);
          af[6]=(short)f2bf(u1.z); af[7]=(short)f2bf(u1.w);
        }else{
          af = *(const bf16x8*)((const unsigned short*)Ap + (size_t)r*128 + k0);
        }
      }
      a[rt]=af;
    }
    #pragma unroll
    for(int nt=0;nt<8;nt++){
      bf16x8 b = *(const bf16x8*)&sWT[(nt*16+n)*136 + k0];
      #pragma unroll
      for(int rt=0;rt<2;rt++)
        acc[nt][rt]=__builtin_amdgcn_mfma_f32_16x16x32_bf16(a[rt], b, acc[nt][rt], 0,0,0);
    }
  }

  __syncthreads();                        // reuse smem for stats partials
  float* sS=(float*)smem;                 // [16][132]
  float* sQ=sS + 16*132;                  // [16][132]
  #pragma unroll
  for(int nt=0;nt<8;nt++){
    int c=nt*16+n;
    float bc=bias[c];
    float s=0.f,q=0.f;
    #pragma unroll
    for(int rt=0;rt<2;rt++){
      #pragma unroll
      for(int i=0;i<4;i++){
        int r=r0w + rt*16 + quad*4 + i;
        if(r<N){
          float z=acc[nt][rt][i]+bc;
          Zb[(size_t)r*128+c]=f2bf(z);
          s+=z; q+=z*z;
        }
      }
    }
    sS[(w*4+quad)*132+c]=s;
    sQ[(w*4+quad)*132+c]=q;
  }
  __syncthreads();
  if(t<128){
    float* st = stats + ((bid&(SREP-1))<<8);   // replica (contention /8)
    float s=0.f,q=0.f;
    #pragma unroll
    for(int g=0;g<16;g++){ s+=sS[g*132+t]; q+=sQ[g*132+t]; }
    atomicAdd(&st[t],s); atomicAdd(&st[128+t],q);
  }
}

// ---- standalone GEMM kernel (layers 1 & 2, bf16 A) ----
template<bool F32A>
__global__ __launch_bounds__(256,3) void k_gemm_bn(const void* __restrict__ Ap,
    const unsigned short* __restrict__ Wt, const float* __restrict__ bias,
    unsigned short* __restrict__ Zb, float* __restrict__ stats, int N){
  __shared__ __align__(16) char smem[34816];
  gemm_bn_body<F32A>(Ap, Wt, bias, Zb, stats, N, blockIdx.x, smem);
}

// ---- packed: [gemm1 (GB blocks, f32 A) | bfill2] ----
__global__ __launch_bounds__(256,3) void k_g1bf(const float* __restrict__ x,
    const unsigned short* __restrict__ Wt, const float* __restrict__ bias,
    unsigned short* __restrict__ Zb, float* __restrict__ stats, int N, int GB,
    const int* __restrict__ row, const int* __restrict__ col,
    const float* __restrict__ ew, int E, int B,
    const int* __restrict__ cntm, const int* __restrict__ bbase,
    uint2* __restrict__ stg){
  __shared__ __align__(16) char smem[34816];
  int bid=blockIdx.x;
  if(bid<GB) gemm_bn_body<true>(x, Wt, bias, Zb, stats, N, bid, smem);
  else       bfill2_body(row, col, ew, E, B, cntm, bbase, stg, bid-GB, smem);
}

// ---------------- apply: BN finalize (8-replica sum) + scale/shift + ReLU + residual ----------------
template<bool OUTF32, bool BNRES>
__global__ __launch_bounds__(256) void k_apply(const unsigned short* __restrict__ Zb,
    const float* __restrict__ stats, const float* __restrict__ gamma,
    const float* __restrict__ beta, float invN,
    const unsigned short* __restrict__ res,
    const float* __restrict__ rstats, const float* __restrict__ rgamma,
    const float* __restrict__ rbeta,
    float* __restrict__ outf, unsigned short* __restrict__ outb, int n16){
  __shared__ float smi[512];
  int t=threadIdx.x;
  if(t<128){
    float s1=0.f,q1=0.f;
    #pragma unroll
    for(int r2=0;r2<SREP;r2++){ s1+=stats[r2*256+t]; q1+=stats[r2*256+128+t]; }
    float mean=s1*invN;
    float var=q1*invN - mean*mean;
    float sc=rsqrtf(var+EPS)*gamma[t];
    smi[t]=sc; smi[128+t]=beta[t]-mean*sc;
    if(BNRES){
      float rs1=0.f,rq1=0.f;
      #pragma unroll
      for(int r2=0;r2<SREP;r2++){ rs1+=rstats[r2*256+t]; rq1+=rstats[r2*256+128+t]; }
      float rm=rs1*invN;
      float rv=rq1*invN - rm*rm;
      float rs=rsqrtf(rv+EPS)*rgamma[t];
      smi[256+t]=rs; smi[384+t]=rbeta[t]-rm*rs;
    }
  }
  __syncthreads();
  int i=blockIdx.x*256+t;
  if(i>=n16) return;
  int c=(i&15)*8;
  uint4 zu=((const uint4*)Zb)[i];
  float z[8]={bflo(zu.x),bfhi(zu.x),bflo(zu.y),bfhi(zu.y),
              bflo(zu.z),bfhi(zu.z),bflo(zu.w),bfhi(zu.w)};
  float o[8];
  #pragma unroll
  for(int k=0;k<8;k++) o[k]=fmaxf(fmaf(z[k],smi[c+k],smi[128+c+k]),0.f);
  if(res){
    uint4 ru=((const uint4*)res)[i];
    float r[8]={bflo(ru.x),bfhi(ru.x),bflo(ru.y),bfhi(ru.y),
                bflo(ru.z),bfhi(ru.z),bflo(ru.w),bfhi(ru.w)};
    if(BNRES){
      #pragma unroll
      for(int k=0;k<8;k++) r[k]=fmaxf(fmaf(r[k],smi[256+c+k],smi[384+c+k]),0.f);
    }
    #pragma unroll
    for(int k=0;k<8;k++) o[k]+=r[k];
  }
  if(OUTF32){
    float4 oa={o[0],o[1],o[2],o[3]}, ob={o[4],o[5],o[6],o[7]};
    ((float4*)outf)[2*i]  =oa;
    ((float4*)outf)[2*i+1]=ob;
  }else{
    uint4 pk;
    pk.x=pack_bf16(o[0],o[1]); pk.y=pack_bf16(o[2],o[3]);
    pk.z=pack_bf16(o[4],o[5]); pk.w=pack_bf16(o[6],o[7]);
    ((uint4*)outb)[i]=pk;
  }
}

extern "C" void kernel_launch(void* const* d_in, const int* in_sizes, int n_in,
                              void* d_out, int out_size, void* d_ws, size_t ws_size,
                              hipStream_t stream){
  const float* x      = (const float*)d_in[0];
  const int*   ei     = (const int*)  d_in[1];
  const float* ew     = (const float*)d_in[2];
  const float* fc_w   = (const float*)d_in[3];
  const float* fc_b   = (const float*)d_in[4];
  const float* conv_w = (const float*)d_in[5];
  const float* conv_b = (const float*)d_in[6];
  const float* gamma  = (const float*)d_in[7];
  const float* beta   = (const float*)d_in[8];
  float* out = (float*)d_out;

  int N = in_sizes[0]/H;
  int E = in_sizes[2];
  const int* row = ei;
  const int* col = ei + E;
  int B = (N+NPB-1)/NPB;                 // buckets (<=512)
  int GF = (E+4095)/4096;                // bfill blocks (<=512)

  // workspace layout (~79 MB)
  size_t NH = (size_t)N*H;
  unsigned short* Wt   = (unsigned short*)d_ws;  // 3*17408 bf16 (pitch-136 WT)
  unsigned short* zb   = Wt + 3*17408;           // N*H bf16: z0, then h1
  unsigned short* hbuf = zb + NH;                // N*H bf16: agg / z1 / z2
  uint2*  stg    = (uint2*)(hbuf + NH);          // E bucket-grouped records
  float2* pairs  = (float2*)(stg + E);           // E final CSR records (val = ew*dnorm[row])
  float*  stats  = (float*)(pairs + E);          // 3 stages x SREP x 256 (memset)
  int*    btot   = (int*)(stats + 3*SREP*256);   // 512
  int*    bbase  = btot + 512;                   // 513
  float*  dnorm  = (float*)(bbase + 513);        // N
  int*    rowptr = (int*)(dnorm + N);            // N+1
  int*    cntm   = rowptr + N + 1;               // 512*512 partition matrix

  hipMemsetAsync(stats, 0, sizeof(float)*3*SREP*256, stream);

  int GB=(N+127)/128;

  // packed: wconv (192) | bcount2 (GF) — per-block histograms, no global atomics
  k_wb<<<192+GF,256,0,stream>>>(fc_w, conv_w, Wt, 192, col, E, cntm);
  k_colscan<<<B,512,0,stream>>>(cntm, GF, btot);
  k_bscan<<<1,512,0,stream>>>(btot, B, E, bbase);
  // packed: gemm1 z0 = x@fc_w+fc_b (GB blocks) | bfill2 (GF, single-pass, LDS-only atomics)
  k_g1bf<<<GB+GF,256,0,stream>>>(x, Wt, fc_b, zb, stats, N, GB,
                                 row, col, ew, E, B, cntm, bbase, stg);
  k_p2a<<<B,256,0,stream>>>(stg,bbase,N,E,dnorm,rowptr);
  k_p2b<<<B,256,0,stream>>>(stg,bbase,N,rowptr,dnorm,pairs);

  int gApply=((N*16)+255)/256;
  int gSpmm=(N+3)/4;
  float invN=1.f/(float)N;

  // layer 0: agg = A_hat @ relu(bn0(z0))  [BN0 inline in gather, 8-replica stats]
  k_spmm_bf<true><<<gSpmm,256,0,stream>>>(pairs,rowptr,dnorm, zb, hbuf, N,
                                          stats, gamma, beta, invN);
  k_gemm_bn<false><<<GB,256,0,stream>>>(hbuf, Wt+17408, conv_b, hbuf, stats+SREP*256, N);
  // h1 = relu(bn1(z1)) + relu(bn0(z0))  -> zb (in-place over z0)
  k_apply<false,true><<<gApply,256,0,stream>>>(hbuf, stats+SREP*256, gamma+H, beta+H, invN,
                                               zb, stats, gamma, beta,
                                               nullptr, zb, N*16);

  // layer 1: out = relu(bn2(agg(h1) @ W1 + b1)) + h1 -> fp32 d_out
  k_spmm_bf<false><<<gSpmm,256,0,stream>>>(pairs,rowptr,dnorm, zb, hbuf, N,
                                           nullptr, nullptr, nullptr, 0.f);
  k_gemm_bn<false><<<GB,256,0,stream>>>(hbuf, Wt+2*17408, conv_b+H, hbuf, stats+2*SREP*256, N);
  k_apply<true,false><<<gApply,256,0,stream>>>(hbuf, stats+2*SREP*256, gamma+2*H, beta+2*H, invN,
                                               zb, nullptr, nullptr, nullptr,
                                               out, nullptr, N*16);
}